// Round 9
// baseline (1497.520 us; speedup 1.0000x reference)
//
#include <hip/hip_runtime.h>
#include <hip/hip_bf16.h>
#include <cstdint>
#include <cstddef>

#define N_ATOMS 10000
#define NSTRUCT 100
#define NP 4
#define NS 4
#define NFEAT 4096
#define HID 256
#define APAD 10240   // 80 tiles of 128

typedef __attribute__((ext_vector_type(8))) _Float16 f16x8;
typedef __attribute__((ext_vector_type(8))) ushort u16x8;
typedef __attribute__((ext_vector_type(4))) float f32x4;

__device__ __forceinline__ float silu(float x) {
  return x / (1.f + __expf(-x));
}
__device__ __forceinline__ ushort f2h(float x) {
  _Float16 h = (_Float16)x;
  return *reinterpret_cast<ushort*>(&h);
}

typedef __attribute__((address_space(3))) uint32_t lds_u32;
typedef const __attribute__((address_space(1))) uint32_t glb_u32;
__device__ __forceinline__ void glds16(const ushort* g, ushort* l) {
  __builtin_amdgcn_global_load_lds((glb_u32*)g, (lds_u32*)l, 16, 0, 0);
}

// ---------------- Kernel A: power spectrum -> fp16, 8-wide chunks ----------
__global__ __launch_bounds__(256) void feat_kernel(
    const float* __restrict__ c0, const float* __restrict__ c1,
    const float* __restrict__ c2, const float* __restrict__ c3,
    ushort* __restrict__ fh) {
  int a = blockIdx.x;
  __shared__ float cs[512];
  int tid = threadIdx.x;
  for (int e = tid; e < 512; e += 256) {
    float v;
    if (e < 32)       v = c0[a * 32  + e];
    else if (e < 128) v = c1[a * 96  + (e - 32)];
    else if (e < 288) v = c2[a * 160 + (e - 128)];
    else              v = c3[a * 224 + (e - 288)];
    cs[e] = v;
  }
  __syncthreads();
  const float cg[4]  = {1.0f, 0.5773502691896258f, 0.4472135954999579f, 0.3779644730092272f};
  const int  off[4]  = {0, 32, 128, 288};
  const int  nm[4]   = {1, 3, 5, 7};
#pragma unroll
  for (int it = 0; it < 2; ++it) {
    int cc = tid + it * 256;          // chunk id in [0,512)
    int l = cc >> 7;
    int rem = cc & 127;
    int q = rem >> 2, rc = (rem & 3) * 8;
    const float* base = cs + off[l];
    float s[8] = {0.f, 0.f, 0.f, 0.f, 0.f, 0.f, 0.f, 0.f};
    for (int m = 0; m < nm[l]; ++m) {
      float bq = base[m * 32 + q];                       // wave-broadcast
      float4 v0 = *reinterpret_cast<const float4*>(&base[m * 32 + rc]);
      float4 v1 = *reinterpret_cast<const float4*>(&base[m * 32 + rc + 4]);
      s[0] += bq * v0.x; s[1] += bq * v0.y; s[2] += bq * v0.z; s[3] += bq * v0.w;
      s[4] += bq * v1.x; s[5] += bq * v1.y; s[6] += bq * v1.z; s[7] += bq * v1.w;
    }
    u16x8 o;
#pragma unroll
    for (int t = 0; t < 8; ++t) o[t] = f2h(s[t] * cg[l]);
    *reinterpret_cast<u16x8*>(&fh[(size_t)a * NFEAT + cc * 8]) = o;
  }
}

// ---------------- Kernel A2: W0 [p][k][n] fp32 -> W0t [p][n][k] fp16 --------
__global__ __launch_bounds__(256) void w0cvt_kernel(
    const float* __restrict__ W0, ushort* __restrict__ W0t) {
  __shared__ float t[32][33];
  int p = blockIdx.z;
  int kt = blockIdx.y * 32, nt = blockIdx.x * 32;
  int lx = threadIdx.x & 31, ly = threadIdx.x >> 5;
  const float* src = W0 + (size_t)p * NFEAT * HID;
#pragma unroll
  for (int i = 0; i < 4; ++i) {
    int k = kt + ly + i * 8;
    t[ly + i * 8][lx] = src[(size_t)k * HID + nt + lx];
  }
  __syncthreads();
  ushort* dst = W0t + (size_t)p * HID * NFEAT;
#pragma unroll
  for (int i = 0; i < 4; ++i) {
    int n = nt + ly + i * 8;
    dst[(size_t)n * NFEAT + kt + lx] = f2h(t[lx][ly + i * 8]);
  }
}

// ---------------- Kernel A3: W1 [p][k][n] fp32 -> W1t [p][n][k] fp16 --------
__global__ __launch_bounds__(256) void w1cvt_kernel(
    const float* __restrict__ W1, ushort* __restrict__ W1t) {
  __shared__ float t[32][33];
  int p = blockIdx.z;
  int kt = blockIdx.y * 32, nt = blockIdx.x * 32;
  int lx = threadIdx.x & 31, ly = threadIdx.x >> 5;
  const float* src = W1 + (size_t)p * HID * HID;
#pragma unroll
  for (int i = 0; i < 4; ++i) {
    int k = kt + ly + i * 8;
    t[ly + i * 8][lx] = src[(size_t)k * HID + nt + lx];
  }
  __syncthreads();
  ushort* dst = W1t + (size_t)p * HID * HID;
#pragma unroll
  for (int i = 0; i < 4; ++i) {
    int n = nt + ly + i * 8;
    dst[(size_t)n * HID + kt + lx] = f2h(t[lx][ly + i * 8]);
  }
}

// ---------------- Kernel B: fp16 MFMA GEMM0, 128x64 tile, BK=32 ------------
// A LDS: 64 phys rows x 128B (logical 128 m x 32 k), chunk XOR by row&7.
// B LDS: 32 phys rows x 128B (logical 64 n x 32 k), same scheme.
// Grid 1280 = 80 m-tiles x 16 n-tiles; XCD remap: l&7 = m-group.
__global__ __launch_bounds__(256) void gemm0_mfma(
    const ushort* __restrict__ fh, const ushort* __restrict__ W0t,
    const float* __restrict__ combW, const int* __restrict__ species,
    ushort* __restrict__ h0f) {
  __shared__ ushort As[64 * 64];   // 8KB
  __shared__ ushort Bs[32 * 64];   // 4KB
  int tid = threadIdx.x;
  int l = blockIdx.y * 16 + blockIdx.x;
  int bm = ((l >> 7) * 8 + (l & 7)) * 128;
  int bn = ((l >> 3) & 15) * 64;
  int wid = tid >> 6, lane = tid & 63;
  int wm = (wid >> 1) * 64;              // 0 / 64
  int wn = (wid & 1) * 32;               // 0 / 32

  // staging decode: thread -> (pr, pc); lg = pc^(pr&7) -> {half, k-chunk}
  int pr = tid >> 3, pc = tid & 7;
  int lg = pc ^ (pr & 7);
  int half = lg >> 2, kc = lg & 3;
  const ushort* gaA1 = fh  + ((size_t)(bm + pr + 64 * half) * NFEAT + kc * 8);
  const ushort* gaA2 = gaA1 + (size_t)32 * NFEAT;
  const ushort* gaB  = W0t + ((size_t)(bn + pr + 32 * half) * NFEAT + kc * 8);
  ushort* lA = As + tid * 8;
  ushort* lB = Bs + tid * 8;

  f32x4 acc[4][2];
#pragma unroll
  for (int i = 0; i < 4; ++i)
#pragma unroll
    for (int j = 0; j < 2; ++j) acc[i][j] = (f32x4){0.f, 0.f, 0.f, 0.f};

  int mrow = lane & 15;
  int h7 = mrow & 7;
  int qv = lane >> 4;
  int pcA = (((wm >> 6) << 2) | qv) ^ h7;
  int pcB = (((wn >> 5) << 2) | qv) ^ h7;

  for (int k0 = 0; k0 < NFEAT; k0 += 32) {
    glds16(gaA1 + k0, lA);
    glds16(gaA2 + k0, lA + 2048);
    glds16(gaB + k0,  lB);
    __syncthreads();

    f16x8 af[4], bf[2];
#pragma unroll
    for (int i = 0; i < 4; ++i)
      af[i] = *reinterpret_cast<const f16x8*>(&As[(i * 16 + mrow) * 64 + pcA * 8]);
#pragma unroll
    for (int j = 0; j < 2; ++j)
      bf[j] = *reinterpret_cast<const f16x8*>(&Bs[(j * 16 + mrow) * 64 + pcB * 8]);
#pragma unroll
    for (int i = 0; i < 4; ++i)
#pragma unroll
      for (int j = 0; j < 2; ++j)
        acc[i][j] = __builtin_amdgcn_mfma_f32_16x16x32_f16(af[i], bf[j], acc[i][j], 0, 0, 0);
    __syncthreads();
  }

  int p = bn >> 8;
  int col = lane & 15, rbase = (lane >> 4) * 4;
#pragma unroll
  for (int i = 0; i < 4; ++i) {
#pragma unroll
    for (int r = 0; r < 4; ++r) {
      int m = bm + wm + i * 16 + rbase + r;
      bool live = (m < N_ATOMS);
      float pw = live ? combW[p * NS + species[m]] : 0.f;
#pragma unroll
      for (int j = 0; j < 2; ++j) {
        int n = bn + wn + j * 16 + col;
        float v = live ? silu(pw * acc[i][j][r]) : 0.f;
        h0f[(size_t)m * 1024 + n] = f2h(v);
      }
    }
  }
}

// ---------------- Kernel C: layer-1 MFMA + silu + W2 dot + segment-sum -----
// Same 128x64 tiling, K=256. Epilogue: part = sum_j silu(acc)*W2[n],
// shfl-reduce over 16 col-lanes, atomicAdd per row into out[sid[m]].
__global__ __launch_bounds__(256) void mlp1_mfma(
    const ushort* __restrict__ h0f, const ushort* __restrict__ W1t,
    const float* __restrict__ W2, const int* __restrict__ sid,
    float* __restrict__ out) {
  __shared__ ushort As[64 * 64];   // 8KB
  __shared__ ushort Bs[32 * 64];   // 4KB
  int tid = threadIdx.x;
  int bm = blockIdx.y * 128;
  int bn = blockIdx.x * 64;        // global n in [0,1024)
  int p  = bn >> 8;
  int wid = tid >> 6, lane = tid & 63;
  int wm = (wid >> 1) * 64;
  int wn = (wid & 1) * 32;

  int pr = tid >> 3, pc = tid & 7;
  int lg = pc ^ (pr & 7);
  int half = lg >> 2, kc = lg & 3;
  const ushort* gaA1 = h0f + ((size_t)(bm + pr + 64 * half) * 1024 + p * 256 + kc * 8);
  const ushort* gaA2 = gaA1 + (size_t)32 * 1024;
  const ushort* gaB  = W1t + (size_t)p * HID * HID
                     + ((size_t)((bn & 255) + pr + 32 * half) * 256 + kc * 8);
  ushort* lA = As + tid * 8;
  ushort* lB = Bs + tid * 8;

  f32x4 acc[4][2];
#pragma unroll
  for (int i = 0; i < 4; ++i)
#pragma unroll
    for (int j = 0; j < 2; ++j) acc[i][j] = (f32x4){0.f, 0.f, 0.f, 0.f};

  int mrow = lane & 15;
  int h7 = mrow & 7;
  int qv = lane >> 4;
  int pcA = (((wm >> 6) << 2) | qv) ^ h7;
  int pcB = (((wn >> 5) << 2) | qv) ^ h7;

  for (int k0 = 0; k0 < 256; k0 += 32) {
    glds16(gaA1 + k0, lA);
    glds16(gaA2 + k0, lA + 2048);
    glds16(gaB + k0,  lB);
    __syncthreads();

    f16x8 af[4], bf[2];
#pragma unroll
    for (int i = 0; i < 4; ++i)
      af[i] = *reinterpret_cast<const f16x8*>(&As[(i * 16 + mrow) * 64 + pcA * 8]);
#pragma unroll
    for (int j = 0; j < 2; ++j)
      bf[j] = *reinterpret_cast<const f16x8*>(&Bs[(j * 16 + mrow) * 64 + pcB * 8]);
#pragma unroll
    for (int i = 0; i < 4; ++i)
#pragma unroll
      for (int j = 0; j < 2; ++j)
        acc[i][j] = __builtin_amdgcn_mfma_f32_16x16x32_f16(af[i], bf[j], acc[i][j], 0, 0, 0);
    __syncthreads();
  }

  // fused layer-2 + segment-sum epilogue
  int col = lane & 15, quad = lane >> 4;
  float w2j0 = W2[bn + wn + col];
  float w2j1 = W2[bn + wn + 16 + col];
  float part[4][4];
#pragma unroll
  for (int i = 0; i < 4; ++i)
#pragma unroll
    for (int r = 0; r < 4; ++r)
      part[i][r] = silu(acc[i][0][r]) * w2j0 + silu(acc[i][1][r]) * w2j1;
#pragma unroll
  for (int i = 0; i < 4; ++i)
#pragma unroll
    for (int r = 0; r < 4; ++r) {
      float v = part[i][r];
      v += __shfl_xor(v, 1, 64);
      v += __shfl_xor(v, 2, 64);
      v += __shfl_xor(v, 4, 64);
      v += __shfl_xor(v, 8, 64);
      part[i][r] = v;
    }
  if (col == 0) {
#pragma unroll
    for (int i = 0; i < 4; ++i)
#pragma unroll
      for (int r = 0; r < 4; ++r) {
        int m = bm + wm + i * 16 + quad * 4 + r;
        if (m < N_ATOMS) atomicAdd(&out[sid[m]], part[i][r]);
      }
  }
}

extern "C" void kernel_launch(void* const* d_in, const int* in_sizes, int n_in,
                              void* d_out, int out_size, void* d_ws, size_t ws_size,
                              hipStream_t stream) {
  const float* c0      = (const float*)d_in[0];
  const float* c1      = (const float*)d_in[1];
  const float* c2      = (const float*)d_in[2];
  const float* c3      = (const float*)d_in[3];
  const int*   species = (const int*)d_in[4];
  const int*   sid     = (const int*)d_in[5];
  const float* combW   = (const float*)d_in[6];
  const float* W0      = (const float*)d_in[7];
  const float* W1      = (const float*)d_in[8];
  const float* W2      = (const float*)d_in[9];
  float*       out     = (float*)d_out;

  // ws: fh 83.9MB | W0t 8.4MB | W1t 0.5MB | h0f 21MB = ~114MB
  ushort* fh  = (ushort*)d_ws;
  ushort* W0t = fh  + (size_t)APAD * NFEAT;
  ushort* W1t = W0t + (size_t)NP * HID * NFEAT;
  ushort* h0f = W1t + (size_t)NP * HID * HID;

  (void)hipMemsetAsync(out, 0, (size_t)out_size * sizeof(float), stream);
  (void)hipMemsetAsync(fh + (size_t)N_ATOMS * NFEAT, 0,
                       (size_t)(APAD - N_ATOMS) * NFEAT * sizeof(ushort), stream);

  feat_kernel<<<N_ATOMS, 256, 0, stream>>>(c0, c1, c2, c3, fh);

  dim3 gw(HID / 32, NFEAT / 32, NP);
  w0cvt_kernel<<<gw, 256, 0, stream>>>(W0, W0t);
  dim3 gw1(HID / 32, HID / 32, NP);
  w1cvt_kernel<<<gw1, 256, 0, stream>>>(W1, W1t);

  dim3 g2(16, APAD / 128);   // 16 n-tiles x 80 m-tiles (XCD-remapped inside)
  gemm0_mfma<<<g2, 256, 0, stream>>>(fh, W0t, combW, species, h0f);

  dim3 g3(16, APAD / 128);
  mlp1_mfma<<<g3, 256, 0, stream>>>(h0f, W1t, W2, sid, out);
}

// Round 10
// 286.930 us; speedup vs baseline: 5.2191x; 5.2191x over previous
//
#include <hip/hip_runtime.h>
#include <hip/hip_bf16.h>
#include <cstdint>
#include <cstddef>

#define N_ATOMS 10000
#define NSTRUCT 100
#define NP 4
#define NS 4
#define NFEAT 4096
#define HID 256
#define APAD 10240   // 80 tiles of 128

typedef __attribute__((ext_vector_type(8))) _Float16 f16x8;
typedef __attribute__((ext_vector_type(8))) ushort u16x8;
typedef __attribute__((ext_vector_type(4))) float f32x4;

__device__ __forceinline__ float silu(float x) {
  return x / (1.f + __expf(-x));
}
__device__ __forceinline__ ushort f2h(float x) {
  _Float16 h = (_Float16)x;
  return *reinterpret_cast<ushort*>(&h);
}

typedef __attribute__((address_space(3))) uint32_t lds_u32;
typedef const __attribute__((address_space(1))) uint32_t glb_u32;
__device__ __forceinline__ void glds16(const ushort* g, ushort* l) {
  __builtin_amdgcn_global_load_lds((glb_u32*)g, (lds_u32*)l, 16, 0, 0);
}

// ---------------- Kernel A: power spectrum -> fp16, 8-wide chunks ----------
__global__ __launch_bounds__(256) void feat_kernel(
    const float* __restrict__ c0, const float* __restrict__ c1,
    const float* __restrict__ c2, const float* __restrict__ c3,
    ushort* __restrict__ fh) {
  int a = blockIdx.x;
  __shared__ float cs[512];
  int tid = threadIdx.x;
  for (int e = tid; e < 512; e += 256) {
    float v;
    if (e < 32)       v = c0[a * 32  + e];
    else if (e < 128) v = c1[a * 96  + (e - 32)];
    else if (e < 288) v = c2[a * 160 + (e - 128)];
    else              v = c3[a * 224 + (e - 288)];
    cs[e] = v;
  }
  __syncthreads();
  const float cg[4]  = {1.0f, 0.5773502691896258f, 0.4472135954999579f, 0.3779644730092272f};
  const int  off[4]  = {0, 32, 128, 288};
  const int  nm[4]   = {1, 3, 5, 7};
#pragma unroll
  for (int it = 0; it < 2; ++it) {
    int cc = tid + it * 256;          // chunk id in [0,512)
    int l = cc >> 7;
    int rem = cc & 127;
    int q = rem >> 2, rc = (rem & 3) * 8;
    const float* base = cs + off[l];
    float s[8] = {0.f, 0.f, 0.f, 0.f, 0.f, 0.f, 0.f, 0.f};
    for (int m = 0; m < nm[l]; ++m) {
      float bq = base[m * 32 + q];                       // wave-broadcast
      float4 v0 = *reinterpret_cast<const float4*>(&base[m * 32 + rc]);
      float4 v1 = *reinterpret_cast<const float4*>(&base[m * 32 + rc + 4]);
      s[0] += bq * v0.x; s[1] += bq * v0.y; s[2] += bq * v0.z; s[3] += bq * v0.w;
      s[4] += bq * v1.x; s[5] += bq * v1.y; s[6] += bq * v1.z; s[7] += bq * v1.w;
    }
    u16x8 o;
#pragma unroll
    for (int t = 0; t < 8; ++t) o[t] = f2h(s[t] * cg[l]);
    *reinterpret_cast<u16x8*>(&fh[(size_t)a * NFEAT + cc * 8]) = o;
  }
}

// ---------------- Kernel A2: W0 [p][k][n] fp32 -> W0t [p][n][k] fp16 --------
__global__ __launch_bounds__(256) void w0cvt_kernel(
    const float* __restrict__ W0, ushort* __restrict__ W0t) {
  __shared__ float t[32][33];
  int p = blockIdx.z;
  int kt = blockIdx.y * 32, nt = blockIdx.x * 32;
  int lx = threadIdx.x & 31, ly = threadIdx.x >> 5;
  const float* src = W0 + (size_t)p * NFEAT * HID;
#pragma unroll
  for (int i = 0; i < 4; ++i) {
    int k = kt + ly + i * 8;
    t[ly + i * 8][lx] = src[(size_t)k * HID + nt + lx];
  }
  __syncthreads();
  ushort* dst = W0t + (size_t)p * HID * NFEAT;
#pragma unroll
  for (int i = 0; i < 4; ++i) {
    int n = nt + ly + i * 8;
    dst[(size_t)n * NFEAT + kt + lx] = f2h(t[lx][ly + i * 8]);
  }
}

// ---------------- Kernel A3: W1 [p][k][n] fp32 -> W1t [p][n][k] fp16 --------
__global__ __launch_bounds__(256) void w1cvt_kernel(
    const float* __restrict__ W1, ushort* __restrict__ W1t) {
  __shared__ float t[32][33];
  int p = blockIdx.z;
  int kt = blockIdx.y * 32, nt = blockIdx.x * 32;
  int lx = threadIdx.x & 31, ly = threadIdx.x >> 5;
  const float* src = W1 + (size_t)p * HID * HID;
#pragma unroll
  for (int i = 0; i < 4; ++i) {
    int k = kt + ly + i * 8;
    t[ly + i * 8][lx] = src[(size_t)k * HID + nt + lx];
  }
  __syncthreads();
  ushort* dst = W1t + (size_t)p * HID * HID;
#pragma unroll
  for (int i = 0; i < 4; ++i) {
    int n = nt + ly + i * 8;
    dst[(size_t)n * HID + kt + lx] = f2h(t[lx][ly + i * 8]);
  }
}

// ---------------- Kernel B: fp16 MFMA GEMM0, 128x64 tile, BK=32 ------------
// A LDS: 64 phys rows x 128B (logical 128 m x 32 k), chunk XOR by row&7.
// B LDS: 32 phys rows x 128B (logical 64 n x 32 k), same scheme.
// Grid 1280 = 80 m-tiles x 16 n-tiles; XCD remap: l&7 = m-group.
__global__ __launch_bounds__(256) void gemm0_mfma(
    const ushort* __restrict__ fh, const ushort* __restrict__ W0t,
    const float* __restrict__ combW, const int* __restrict__ species,
    ushort* __restrict__ h0f) {
  __shared__ ushort As[64 * 64];   // 8KB
  __shared__ ushort Bs[32 * 64];   // 4KB
  int tid = threadIdx.x;
  int l = blockIdx.y * 16 + blockIdx.x;
  int bm = ((l >> 7) * 8 + (l & 7)) * 128;
  int bn = ((l >> 3) & 15) * 64;
  int wid = tid >> 6, lane = tid & 63;
  int wm = (wid >> 1) * 64;              // 0 / 64
  int wn = (wid & 1) * 32;               // 0 / 32

  int pr = tid >> 3, pc = tid & 7;
  int lg = pc ^ (pr & 7);
  int half = lg >> 2, kc = lg & 3;
  const ushort* gaA1 = fh  + ((size_t)(bm + pr + 64 * half) * NFEAT + kc * 8);
  const ushort* gaA2 = gaA1 + (size_t)32 * NFEAT;
  const ushort* gaB  = W0t + ((size_t)(bn + pr + 32 * half) * NFEAT + kc * 8);
  ushort* lA = As + tid * 8;
  ushort* lB = Bs + tid * 8;

  f32x4 acc[4][2];
#pragma unroll
  for (int i = 0; i < 4; ++i)
#pragma unroll
    for (int j = 0; j < 2; ++j) acc[i][j] = (f32x4){0.f, 0.f, 0.f, 0.f};

  int mrow = lane & 15;
  int h7 = mrow & 7;
  int qv = lane >> 4;
  int pcA = (((wm >> 6) << 2) | qv) ^ h7;
  int pcB = (((wn >> 5) << 2) | qv) ^ h7;

  for (int k0 = 0; k0 < NFEAT; k0 += 32) {
    glds16(gaA1 + k0, lA);
    glds16(gaA2 + k0, lA + 2048);
    glds16(gaB + k0,  lB);
    __syncthreads();

    f16x8 af[4], bf[2];
#pragma unroll
    for (int i = 0; i < 4; ++i)
      af[i] = *reinterpret_cast<const f16x8*>(&As[(i * 16 + mrow) * 64 + pcA * 8]);
#pragma unroll
    for (int j = 0; j < 2; ++j)
      bf[j] = *reinterpret_cast<const f16x8*>(&Bs[(j * 16 + mrow) * 64 + pcB * 8]);
#pragma unroll
    for (int i = 0; i < 4; ++i)
#pragma unroll
      for (int j = 0; j < 2; ++j)
        acc[i][j] = __builtin_amdgcn_mfma_f32_16x16x32_f16(af[i], bf[j], acc[i][j], 0, 0, 0);
    __syncthreads();
  }

  int p = bn >> 8;
  int col = lane & 15, rbase = (lane >> 4) * 4;
#pragma unroll
  for (int i = 0; i < 4; ++i) {
#pragma unroll
    for (int r = 0; r < 4; ++r) {
      int m = bm + wm + i * 16 + rbase + r;
      bool live = (m < N_ATOMS);
      float pw = live ? combW[p * NS + species[m]] : 0.f;
#pragma unroll
      for (int j = 0; j < 2; ++j) {
        int n = bn + wn + j * 16 + col;
        float v = live ? silu(pw * acc[i][j][r]) : 0.f;
        h0f[(size_t)m * 1024 + n] = f2h(v);
      }
    }
  }
}

// ---------------- Kernel C: layer-1 MFMA + silu + W2 dot + segment-sum -----
// 128x64 tile, K=256. Epilogue: part = sum_j silu(acc)*W2[n], shfl-reduce
// over 16 col-lanes, LDS per-structure staging, ~3 global atomics per block.
__global__ __launch_bounds__(256) void mlp1_mfma(
    const ushort* __restrict__ h0f, const ushort* __restrict__ W1t,
    const float* __restrict__ W2, const int* __restrict__ sid,
    float* __restrict__ out) {
  __shared__ ushort As[64 * 64];   // 8KB
  __shared__ ushort Bs[32 * 64];   // 4KB
  __shared__ float sout[NSTRUCT];
  int tid = threadIdx.x;
  int bm = blockIdx.y * 128;
  int bn = blockIdx.x * 64;        // global n in [0,1024)
  int p  = bn >> 8;
  int wid = tid >> 6, lane = tid & 63;
  int wm = (wid >> 1) * 64;
  int wn = (wid & 1) * 32;

  if (tid < NSTRUCT) sout[tid] = 0.f;

  int pr = tid >> 3, pc = tid & 7;
  int lg = pc ^ (pr & 7);
  int half = lg >> 2, kc = lg & 3;
  const ushort* gaA1 = h0f + ((size_t)(bm + pr + 64 * half) * 1024 + p * 256 + kc * 8);
  const ushort* gaA2 = gaA1 + (size_t)32 * 1024;
  const ushort* gaB  = W1t + (size_t)p * HID * HID
                     + ((size_t)((bn & 255) + pr + 32 * half) * 256 + kc * 8);
  ushort* lA = As + tid * 8;
  ushort* lB = Bs + tid * 8;

  f32x4 acc[4][2];
#pragma unroll
  for (int i = 0; i < 4; ++i)
#pragma unroll
    for (int j = 0; j < 2; ++j) acc[i][j] = (f32x4){0.f, 0.f, 0.f, 0.f};

  int mrow = lane & 15;
  int h7 = mrow & 7;
  int qv = lane >> 4;
  int pcA = (((wm >> 6) << 2) | qv) ^ h7;
  int pcB = (((wn >> 5) << 2) | qv) ^ h7;

  for (int k0 = 0; k0 < 256; k0 += 32) {
    glds16(gaA1 + k0, lA);
    glds16(gaA2 + k0, lA + 2048);
    glds16(gaB + k0,  lB);
    __syncthreads();

    f16x8 af[4], bf[2];
#pragma unroll
    for (int i = 0; i < 4; ++i)
      af[i] = *reinterpret_cast<const f16x8*>(&As[(i * 16 + mrow) * 64 + pcA * 8]);
#pragma unroll
    for (int j = 0; j < 2; ++j)
      bf[j] = *reinterpret_cast<const f16x8*>(&Bs[(j * 16 + mrow) * 64 + pcB * 8]);
#pragma unroll
    for (int i = 0; i < 4; ++i)
#pragma unroll
      for (int j = 0; j < 2; ++j)
        acc[i][j] = __builtin_amdgcn_mfma_f32_16x16x32_f16(af[i], bf[j], acc[i][j], 0, 0, 0);
    __syncthreads();
  }

  // fused layer-2 + segment-sum epilogue (LDS-staged)
  int col = lane & 15, quad = lane >> 4;
  float w2j0 = W2[bn + wn + col];
  float w2j1 = W2[bn + wn + 16 + col];
#pragma unroll
  for (int i = 0; i < 4; ++i) {
#pragma unroll
    for (int r = 0; r < 4; ++r) {
      float v = silu(acc[i][0][r]) * w2j0 + silu(acc[i][1][r]) * w2j1;
      v += __shfl_xor(v, 1, 64);
      v += __shfl_xor(v, 2, 64);
      v += __shfl_xor(v, 4, 64);
      v += __shfl_xor(v, 8, 64);
      if (col == 0) {
        int m = bm + wm + i * 16 + quad * 4 + r;
        if (m < N_ATOMS) atomicAdd(&sout[sid[m]], v);   // LDS atomic
      }
    }
  }
  __syncthreads();
  if (tid < NSTRUCT) {
    float v = sout[tid];
    if (v != 0.f) atomicAdd(&out[tid], v);              // ~2-3 per block
  }
}

extern "C" void kernel_launch(void* const* d_in, const int* in_sizes, int n_in,
                              void* d_out, int out_size, void* d_ws, size_t ws_size,
                              hipStream_t stream) {
  const float* c0      = (const float*)d_in[0];
  const float* c1      = (const float*)d_in[1];
  const float* c2      = (const float*)d_in[2];
  const float* c3      = (const float*)d_in[3];
  const int*   species = (const int*)d_in[4];
  const int*   sid     = (const int*)d_in[5];
  const float* combW   = (const float*)d_in[6];
  const float* W0      = (const float*)d_in[7];
  const float* W1      = (const float*)d_in[8];
  const float* W2      = (const float*)d_in[9];
  float*       out     = (float*)d_out;

  // ws: fh 83.9MB | W0t 8.4MB | W1t 0.5MB | h0f 21MB = ~114MB
  ushort* fh  = (ushort*)d_ws;
  ushort* W0t = fh  + (size_t)APAD * NFEAT;
  ushort* W1t = W0t + (size_t)NP * HID * NFEAT;
  ushort* h0f = W1t + (size_t)NP * HID * HID;

  (void)hipMemsetAsync(out, 0, (size_t)out_size * sizeof(float), stream);
  (void)hipMemsetAsync(fh + (size_t)N_ATOMS * NFEAT, 0,
                       (size_t)(APAD - N_ATOMS) * NFEAT * sizeof(ushort), stream);

  feat_kernel<<<N_ATOMS, 256, 0, stream>>>(c0, c1, c2, c3, fh);

  dim3 gw(HID / 32, NFEAT / 32, NP);
  w0cvt_kernel<<<gw, 256, 0, stream>>>(W0, W0t);
  dim3 gw1(HID / 32, HID / 32, NP);
  w1cvt_kernel<<<gw1, 256, 0, stream>>>(W1, W1t);

  dim3 g2(16, APAD / 128);   // 16 n-tiles x 80 m-tiles (XCD-remapped inside)
  gemm0_mfma<<<g2, 256, 0, stream>>>(fh, W0t, combW, species, h0f);

  dim3 g3(16, APAD / 128);
  mlp1_mfma<<<g3, 256, 0, stream>>>(h0f, W1t, W2, sid, out);
}

// Round 11
// 254.967 us; speedup vs baseline: 5.8734x; 1.1254x over previous
//
#include <hip/hip_runtime.h>
#include <hip/hip_bf16.h>
#include <cstdint>
#include <cstddef>

#define N_ATOMS 10000
#define NSTRUCT 100
#define NP 4
#define NS 4
#define NFEAT 4096
#define HID 256
#define APAD 10240   // 80 tiles of 128

typedef __attribute__((ext_vector_type(8))) _Float16 f16x8;
typedef __attribute__((ext_vector_type(8))) ushort u16x8;
typedef __attribute__((ext_vector_type(4))) float f32x4;

__device__ __forceinline__ float silu(float x) {
  return x / (1.f + __expf(-x));
}
__device__ __forceinline__ ushort f2h(float x) {
  _Float16 h = (_Float16)x;
  return *reinterpret_cast<ushort*>(&h);
}

typedef __attribute__((address_space(3))) uint32_t lds_u32;
typedef const __attribute__((address_space(1))) uint32_t glb_u32;
__device__ __forceinline__ void glds16(const ushort* g, ushort* l) {
  __builtin_amdgcn_global_load_lds((glb_u32*)g, (lds_u32*)l, 16, 0, 0);
}

// ---------------- Kernel A: power spectrum -> fp16, 8-wide chunks ----------
__global__ __launch_bounds__(256) void feat_kernel(
    const float* __restrict__ c0, const float* __restrict__ c1,
    const float* __restrict__ c2, const float* __restrict__ c3,
    ushort* __restrict__ fh) {
  int a = blockIdx.x;
  __shared__ float cs[512];
  int tid = threadIdx.x;
  for (int e = tid; e < 512; e += 256) {
    float v;
    if (e < 32)       v = c0[a * 32  + e];
    else if (e < 128) v = c1[a * 96  + (e - 32)];
    else if (e < 288) v = c2[a * 160 + (e - 128)];
    else              v = c3[a * 224 + (e - 288)];
    cs[e] = v;
  }
  __syncthreads();
  const float cg[4]  = {1.0f, 0.5773502691896258f, 0.4472135954999579f, 0.3779644730092272f};
  const int  off[4]  = {0, 32, 128, 288};
  const int  nm[4]   = {1, 3, 5, 7};
#pragma unroll
  for (int it = 0; it < 2; ++it) {
    int cc = tid + it * 256;          // chunk id in [0,512)
    int l = cc >> 7;
    int rem = cc & 127;
    int q = rem >> 2, rc = (rem & 3) * 8;
    const float* base = cs + off[l];
    float s[8] = {0.f, 0.f, 0.f, 0.f, 0.f, 0.f, 0.f, 0.f};
    for (int m = 0; m < nm[l]; ++m) {
      float bq = base[m * 32 + q];                       // wave-broadcast
      float4 v0 = *reinterpret_cast<const float4*>(&base[m * 32 + rc]);
      float4 v1 = *reinterpret_cast<const float4*>(&base[m * 32 + rc + 4]);
      s[0] += bq * v0.x; s[1] += bq * v0.y; s[2] += bq * v0.z; s[3] += bq * v0.w;
      s[4] += bq * v1.x; s[5] += bq * v1.y; s[6] += bq * v1.z; s[7] += bq * v1.w;
    }
    u16x8 o;
#pragma unroll
    for (int t = 0; t < 8; ++t) o[t] = f2h(s[t] * cg[l]);
    *reinterpret_cast<u16x8*>(&fh[(size_t)a * NFEAT + cc * 8]) = o;
  }
}

// ---------------- Kernel A2: W0 [p][k][n] fp32 -> W0t [p][n][k] fp16 --------
__global__ __launch_bounds__(256) void w0cvt_kernel(
    const float* __restrict__ W0, ushort* __restrict__ W0t) {
  __shared__ float t[32][33];
  int p = blockIdx.z;
  int kt = blockIdx.y * 32, nt = blockIdx.x * 32;
  int lx = threadIdx.x & 31, ly = threadIdx.x >> 5;
  const float* src = W0 + (size_t)p * NFEAT * HID;
#pragma unroll
  for (int i = 0; i < 4; ++i) {
    int k = kt + ly + i * 8;
    t[ly + i * 8][lx] = src[(size_t)k * HID + nt + lx];
  }
  __syncthreads();
  ushort* dst = W0t + (size_t)p * HID * NFEAT;
#pragma unroll
  for (int i = 0; i < 4; ++i) {
    int n = nt + ly + i * 8;
    dst[(size_t)n * NFEAT + kt + lx] = f2h(t[lx][ly + i * 8]);
  }
}

// ---------------- Kernel A3: W1 [p][k][n] fp32 -> W1t [p][n][k] fp16 --------
__global__ __launch_bounds__(256) void w1cvt_kernel(
    const float* __restrict__ W1, ushort* __restrict__ W1t) {
  __shared__ float t[32][33];
  int p = blockIdx.z;
  int kt = blockIdx.y * 32, nt = blockIdx.x * 32;
  int lx = threadIdx.x & 31, ly = threadIdx.x >> 5;
  const float* src = W1 + (size_t)p * HID * HID;
#pragma unroll
  for (int i = 0; i < 4; ++i) {
    int k = kt + ly + i * 8;
    t[ly + i * 8][lx] = src[(size_t)k * HID + nt + lx];
  }
  __syncthreads();
  ushort* dst = W1t + (size_t)p * HID * HID;
#pragma unroll
  for (int i = 0; i < 4; ++i) {
    int n = nt + ly + i * 8;
    dst[(size_t)n * HID + kt + lx] = f2h(t[lx][ly + i * 8]);
  }
}

// ---------------- Kernel B: fp16 MFMA GEMM0, 128x128, BK=32 (R8 shape) -----
// LDS: 64 phys rows x 128B; phys (pr,pc) holds logical (m_half=lg>>2, kc=lg&3)
// of m-row pr + 64*m_half, lg = pc^(pr&7). Conflict-free b128 reads.
// XCD remap: linear&7 = m-group so the 8 n-tiles of an m-tile share one XCD L2.
__global__ __launch_bounds__(256) void gemm0_mfma(
    const ushort* __restrict__ fh, const ushort* __restrict__ W0t,
    const float* __restrict__ combW, const int* __restrict__ species,
    ushort* __restrict__ h0f) {
  __shared__ ushort As[64 * 64];   // 8KB
  __shared__ ushort Bs[64 * 64];   // 8KB
  int tid = threadIdx.x;
  int linear = blockIdx.y * 8 + blockIdx.x;
  int xc = linear & 7, sq = linear >> 3;
  int bm = ((sq >> 3) * 8 + xc) * 128;   // m-tile
  int bn = (sq & 7) * 128;               // n-tile
  int wid = tid >> 6, lane = tid & 63;
  int wm = (wid >> 1) * 64, wn = (wid & 1) * 64;
  int mh = wid >> 1, nh = wid & 1;

  int pr = tid >> 3, pc = tid & 7;
  int lg = pc ^ (pr & 7);
  int mhalf = lg >> 2, kc = lg & 3;
  const ushort* gaA1 = fh  + ((size_t)(bm + pr + 64 * mhalf) * NFEAT + kc * 8);
  const ushort* gaA2 = gaA1 + (size_t)32 * NFEAT;
  const ushort* gaB1 = W0t + ((size_t)(bn + pr + 64 * mhalf) * NFEAT + kc * 8);
  const ushort* gaB2 = gaB1 + (size_t)32 * NFEAT;
  ushort* lA = As + tid * 8;
  ushort* lB = Bs + tid * 8;

  f32x4 acc[4][4];
#pragma unroll
  for (int i = 0; i < 4; ++i)
#pragma unroll
    for (int j = 0; j < 4; ++j) acc[i][j] = (f32x4){0.f, 0.f, 0.f, 0.f};

  int mrow = lane & 15;
  int h7 = mrow & 7;
  int qv = lane >> 4;
  int pcA = ((mh << 2) | qv) ^ h7;
  int pcB = ((nh << 2) | qv) ^ h7;

  for (int k0 = 0; k0 < NFEAT; k0 += 32) {
    glds16(gaA1 + k0, lA);
    glds16(gaA2 + k0, lA + 2048);
    glds16(gaB1 + k0, lB);
    glds16(gaB2 + k0, lB + 2048);
    __syncthreads();

    f16x8 af[4], bf[4];
#pragma unroll
    for (int i = 0; i < 4; ++i) {
      af[i] = *reinterpret_cast<const f16x8*>(&As[(i * 16 + mrow) * 64 + pcA * 8]);
      bf[i] = *reinterpret_cast<const f16x8*>(&Bs[(i * 16 + mrow) * 64 + pcB * 8]);
    }
#pragma unroll
    for (int i = 0; i < 4; ++i)
#pragma unroll
      for (int j = 0; j < 4; ++j)
        acc[i][j] = __builtin_amdgcn_mfma_f32_16x16x32_f16(af[i], bf[j], acc[i][j], 0, 0, 0);
    __syncthreads();
  }

  int p = bn >> 8;
  int col = lane & 15, rbase = (lane >> 4) * 4;
#pragma unroll
  for (int i = 0; i < 4; ++i) {
#pragma unroll
    for (int r = 0; r < 4; ++r) {
      int m = bm + wm + i * 16 + rbase + r;
      bool live = (m < N_ATOMS);
      float pw = live ? combW[p * NS + species[m]] : 0.f;
#pragma unroll
      for (int j = 0; j < 4; ++j) {
        int n = bn + wn + j * 16 + col;
        float v = live ? silu(pw * acc[i][j][r]) : 0.f;
        h0f[(size_t)m * 1024 + n] = f2h(v);
      }
    }
  }
}

// ---------------- Kernel C: layer-1 MFMA + silu + W2 dot + segment-sum -----
// 128x64 tile, K=256. Epilogue: part = sum_j silu(acc)*W2[n], shfl-reduce
// over 16 col-lanes, LDS per-structure staging, ~3 global atomics per block.
__global__ __launch_bounds__(256) void mlp1_mfma(
    const ushort* __restrict__ h0f, const ushort* __restrict__ W1t,
    const float* __restrict__ W2, const int* __restrict__ sid,
    float* __restrict__ out) {
  __shared__ ushort As[64 * 64];   // 8KB
  __shared__ ushort Bs[32 * 64];   // 4KB
  __shared__ float sout[NSTRUCT];
  int tid = threadIdx.x;
  int bm = blockIdx.y * 128;
  int bn = blockIdx.x * 64;        // global n in [0,1024)
  int p  = bn >> 8;
  int wid = tid >> 6, lane = tid & 63;
  int wm = (wid >> 1) * 64;
  int wn = (wid & 1) * 32;

  if (tid < NSTRUCT) sout[tid] = 0.f;

  int pr = tid >> 3, pc = tid & 7;
  int lg = pc ^ (pr & 7);
  int half = lg >> 2, kc = lg & 3;
  const ushort* gaA1 = h0f + ((size_t)(bm + pr + 64 * half) * 1024 + p * 256 + kc * 8);
  const ushort* gaA2 = gaA1 + (size_t)32 * 1024;
  const ushort* gaB  = W1t + (size_t)p * HID * HID
                     + ((size_t)((bn & 255) + pr + 32 * half) * 256 + kc * 8);
  ushort* lA = As + tid * 8;
  ushort* lB = Bs + tid * 8;

  f32x4 acc[4][2];
#pragma unroll
  for (int i = 0; i < 4; ++i)
#pragma unroll
    for (int j = 0; j < 2; ++j) acc[i][j] = (f32x4){0.f, 0.f, 0.f, 0.f};

  int mrow = lane & 15;
  int h7 = mrow & 7;
  int qv = lane >> 4;
  int pcA = (((wm >> 6) << 2) | qv) ^ h7;
  int pcB = (((wn >> 5) << 2) | qv) ^ h7;

  for (int k0 = 0; k0 < 256; k0 += 32) {
    glds16(gaA1 + k0, lA);
    glds16(gaA2 + k0, lA + 2048);
    glds16(gaB + k0,  lB);
    __syncthreads();

    f16x8 af[4], bf[2];
#pragma unroll
    for (int i = 0; i < 4; ++i)
      af[i] = *reinterpret_cast<const f16x8*>(&As[(i * 16 + mrow) * 64 + pcA * 8]);
#pragma unroll
    for (int j = 0; j < 2; ++j)
      bf[j] = *reinterpret_cast<const f16x8*>(&Bs[(j * 16 + mrow) * 64 + pcB * 8]);
#pragma unroll
    for (int i = 0; i < 4; ++i)
#pragma unroll
      for (int j = 0; j < 2; ++j)
        acc[i][j] = __builtin_amdgcn_mfma_f32_16x16x32_f16(af[i], bf[j], acc[i][j], 0, 0, 0);
    __syncthreads();
  }

  // fused layer-2 + segment-sum epilogue (LDS-staged)
  int col = lane & 15, quad = lane >> 4;
  float w2j0 = W2[bn + wn + col];
  float w2j1 = W2[bn + wn + 16 + col];
#pragma unroll
  for (int i = 0; i < 4; ++i) {
#pragma unroll
    for (int r = 0; r < 4; ++r) {
      float v = silu(acc[i][0][r]) * w2j0 + silu(acc[i][1][r]) * w2j1;
      v += __shfl_xor(v, 1, 64);
      v += __shfl_xor(v, 2, 64);
      v += __shfl_xor(v, 4, 64);
      v += __shfl_xor(v, 8, 64);
      if (col == 0) {
        int m = bm + wm + i * 16 + quad * 4 + r;
        if (m < N_ATOMS) atomicAdd(&sout[sid[m]], v);   // LDS atomic
      }
    }
  }
  __syncthreads();
  if (tid < NSTRUCT) {
    float v = sout[tid];
    if (v != 0.f) atomicAdd(&out[tid], v);              // ~2-3 per block
  }
}

extern "C" void kernel_launch(void* const* d_in, const int* in_sizes, int n_in,
                              void* d_out, int out_size, void* d_ws, size_t ws_size,
                              hipStream_t stream) {
  const float* c0      = (const float*)d_in[0];
  const float* c1      = (const float*)d_in[1];
  const float* c2      = (const float*)d_in[2];
  const float* c3      = (const float*)d_in[3];
  const int*   species = (const int*)d_in[4];
  const int*   sid     = (const int*)d_in[5];
  const float* combW   = (const float*)d_in[6];
  const float* W0      = (const float*)d_in[7];
  const float* W1      = (const float*)d_in[8];
  const float* W2      = (const float*)d_in[9];
  float*       out     = (float*)d_out;

  // ws: fh 83.9MB | W0t 8.4MB | W1t 0.5MB | h0f 21MB = ~114MB
  ushort* fh  = (ushort*)d_ws;
  ushort* W0t = fh  + (size_t)APAD * NFEAT;
  ushort* W1t = W0t + (size_t)NP * HID * NFEAT;
  ushort* h0f = W1t + (size_t)NP * HID * HID;

  (void)hipMemsetAsync(out, 0, (size_t)out_size * sizeof(float), stream);
  (void)hipMemsetAsync(fh + (size_t)N_ATOMS * NFEAT, 0,
                       (size_t)(APAD - N_ATOMS) * NFEAT * sizeof(ushort), stream);

  feat_kernel<<<N_ATOMS, 256, 0, stream>>>(c0, c1, c2, c3, fh);

  dim3 gw(HID / 32, NFEAT / 32, NP);
  w0cvt_kernel<<<gw, 256, 0, stream>>>(W0, W0t);
  dim3 gw1(HID / 32, HID / 32, NP);
  w1cvt_kernel<<<gw1, 256, 0, stream>>>(W1, W1t);

  dim3 g2(8, APAD / 128);    // 8 n-tiles x 80 remapped slots (R8 shape)
  gemm0_mfma<<<g2, 256, 0, stream>>>(fh, W0t, combW, species, h0f);

  dim3 g3(16, APAD / 128);   // 16 n-tiles x 80 m-tiles
  mlp1_mfma<<<g3, 256, 0, stream>>>(h0f, W1t, W2, sid, out);
}

// Round 12
// 249.842 us; speedup vs baseline: 5.9939x; 1.0205x over previous
//
#include <hip/hip_runtime.h>
#include <hip/hip_bf16.h>
#include <cstdint>
#include <cstddef>

#define N_ATOMS 10000
#define NSTRUCT 100
#define NP 4
#define NS 4
#define NFEAT 4096
#define HID 256
#define APAD 10240   // 80 tiles of 128

// prep-kernel block ranges
#define PB_FEAT  10000                    // [0, 10000): power spectrum
#define PB_W0    (PB_FEAT + 4096)         // w0cvt: 8 x 128 x 4 tiles
#define PB_W1    (PB_W0 + 256)            // w1cvt: 8 x 8 x 4 tiles
#define PB_ZERO  (PB_W1 + 480)            // fh tail rows 10000..10239
#define PB_TOTAL (PB_ZERO + 1)            // + out zero

typedef __attribute__((ext_vector_type(8))) _Float16 f16x8;
typedef __attribute__((ext_vector_type(8))) ushort u16x8;
typedef __attribute__((ext_vector_type(4))) float f32x4;

__device__ __forceinline__ float silu(float x) {
  return x / (1.f + __expf(-x));
}
__device__ __forceinline__ ushort f2h(float x) {
  _Float16 h = (_Float16)x;
  return *reinterpret_cast<ushort*>(&h);
}

typedef __attribute__((address_space(3))) uint32_t lds_u32;
typedef const __attribute__((address_space(1))) uint32_t glb_u32;
__device__ __forceinline__ void glds16(const ushort* g, ushort* l) {
  __builtin_amdgcn_global_load_lds((glb_u32*)g, (lds_u32*)l, 16, 0, 0);
}

// ---------------- Kernel P: fused prep -------------------------------------
// blocks [0,10000): feat | [..): w0cvt | w1cvt | fh-tail zero | out zero
__global__ __launch_bounds__(256) void prep_kernel(
    const float* __restrict__ c0, const float* __restrict__ c1,
    const float* __restrict__ c2, const float* __restrict__ c3,
    const float* __restrict__ W0, const float* __restrict__ W1,
    ushort* __restrict__ fh, ushort* __restrict__ W0t,
    ushort* __restrict__ W1t, float* __restrict__ out) {
  __shared__ float shbuf[32 * 33];   // feat uses first 512; cvt uses 32x33
  int b = blockIdx.x;
  int tid = threadIdx.x;

  if (b < PB_FEAT) {
    // ---- power spectrum -> fp16 ----
    int a = b;
    float* cs = shbuf;
    for (int e = tid; e < 512; e += 256) {
      float v;
      if (e < 32)       v = c0[a * 32  + e];
      else if (e < 128) v = c1[a * 96  + (e - 32)];
      else if (e < 288) v = c2[a * 160 + (e - 128)];
      else              v = c3[a * 224 + (e - 288)];
      cs[e] = v;
    }
    __syncthreads();
    const float cg[4]  = {1.0f, 0.5773502691896258f, 0.4472135954999579f, 0.3779644730092272f};
    const int  off[4]  = {0, 32, 128, 288};
    const int  nm[4]   = {1, 3, 5, 7};
#pragma unroll
    for (int it = 0; it < 2; ++it) {
      int cc = tid + it * 256;
      int l = cc >> 7;
      int rem = cc & 127;
      int q = rem >> 2, rc = (rem & 3) * 8;
      const float* base = cs + off[l];
      float s[8] = {0.f, 0.f, 0.f, 0.f, 0.f, 0.f, 0.f, 0.f};
      for (int m = 0; m < nm[l]; ++m) {
        float bq = base[m * 32 + q];
        float4 v0 = *reinterpret_cast<const float4*>(&base[m * 32 + rc]);
        float4 v1 = *reinterpret_cast<const float4*>(&base[m * 32 + rc + 4]);
        s[0] += bq * v0.x; s[1] += bq * v0.y; s[2] += bq * v0.z; s[3] += bq * v0.w;
        s[4] += bq * v1.x; s[5] += bq * v1.y; s[6] += bq * v1.z; s[7] += bq * v1.w;
      }
      u16x8 o;
#pragma unroll
      for (int t = 0; t < 8; ++t) o[t] = f2h(s[t] * cg[l]);
      *reinterpret_cast<u16x8*>(&fh[(size_t)a * NFEAT + cc * 8]) = o;
    }
  } else if (b < PB_W0) {
    // ---- W0 [p][k][n] -> W0t [p][n][k] fp16, 32x32 tiles ----
    int idx = b - PB_FEAT;          // 4096 = 8(n) x 128(k) x 4(p)
    int nx = idx & 7, ky = (idx >> 3) & 127, p = idx >> 10;
    int kt = ky * 32, nt = nx * 32;
    int lx = tid & 31, ly = tid >> 5;
    float (*t)[33] = (float(*)[33])shbuf;
    const float* src = W0 + (size_t)p * NFEAT * HID;
#pragma unroll
    for (int i = 0; i < 4; ++i)
      t[ly + i * 8][lx] = src[(size_t)(kt + ly + i * 8) * HID + nt + lx];
    __syncthreads();
    ushort* dst = W0t + (size_t)p * HID * NFEAT;
#pragma unroll
    for (int i = 0; i < 4; ++i)
      dst[(size_t)(nt + ly + i * 8) * NFEAT + kt + lx] = f2h(t[lx][ly + i * 8]);
  } else if (b < PB_W1) {
    // ---- W1 [p][k][n] -> W1t [p][n][k] fp16 ----
    int idx = b - PB_W0;            // 256 = 8 x 8 x 4
    int nx = idx & 7, ky = (idx >> 3) & 7, p = idx >> 6;
    int kt = ky * 32, nt = nx * 32;
    int lx = tid & 31, ly = tid >> 5;
    float (*t)[33] = (float(*)[33])shbuf;
    const float* src = W1 + (size_t)p * HID * HID;
#pragma unroll
    for (int i = 0; i < 4; ++i)
      t[ly + i * 8][lx] = src[(size_t)(kt + ly + i * 8) * HID + nt + lx];
    __syncthreads();
    ushort* dst = W1t + (size_t)p * HID * HID;
#pragma unroll
    for (int i = 0; i < 4; ++i)
      dst[(size_t)(nt + ly + i * 8) * HID + kt + lx] = f2h(t[lx][ly + i * 8]);
  } else if (b < PB_ZERO) {
    // ---- zero fh rows [10000, 10240) : 480 blocks x 2048 ushorts ----
    int idx = b - PB_W1;
    size_t base = (size_t)N_ATOMS * NFEAT + (size_t)idx * 2048 + tid * 8;
    u16x8 z = (u16x8){0, 0, 0, 0, 0, 0, 0, 0};
    *reinterpret_cast<u16x8*>(&fh[base]) = z;
  } else {
    // ---- zero out[100] ----
    if (tid < NSTRUCT) out[tid] = 0.f;
  }
}

// ---------------- Kernel B: fp16 MFMA GEMM0, 128x128, BK=32 (R8 shape) -----
// LDS: 64 phys rows x 128B; phys (pr,pc) holds logical (m_half=lg>>2, kc=lg&3)
// of m-row pr + 64*m_half, lg = pc^(pr&7). Conflict-free b128 reads.
// XCD remap: linear&7 = m-group so the 8 n-tiles of an m-tile share one XCD L2.
__global__ __launch_bounds__(256) void gemm0_mfma(
    const ushort* __restrict__ fh, const ushort* __restrict__ W0t,
    const float* __restrict__ combW, const int* __restrict__ species,
    ushort* __restrict__ h0f) {
  __shared__ ushort As[64 * 64];   // 8KB
  __shared__ ushort Bs[64 * 64];   // 8KB
  int tid = threadIdx.x;
  int linear = blockIdx.y * 8 + blockIdx.x;
  int xc = linear & 7, sq = linear >> 3;
  int bm = ((sq >> 3) * 8 + xc) * 128;   // m-tile
  int bn = (sq & 7) * 128;               // n-tile
  int wid = tid >> 6, lane = tid & 63;
  int wm = (wid >> 1) * 64, wn = (wid & 1) * 64;
  int mh = wid >> 1, nh = wid & 1;

  int pr = tid >> 3, pc = tid & 7;
  int lg = pc ^ (pr & 7);
  int mhalf = lg >> 2, kc = lg & 3;
  const ushort* gaA1 = fh  + ((size_t)(bm + pr + 64 * mhalf) * NFEAT + kc * 8);
  const ushort* gaA2 = gaA1 + (size_t)32 * NFEAT;
  const ushort* gaB1 = W0t + ((size_t)(bn + pr + 64 * mhalf) * NFEAT + kc * 8);
  const ushort* gaB2 = gaB1 + (size_t)32 * NFEAT;
  ushort* lA = As + tid * 8;
  ushort* lB = Bs + tid * 8;

  f32x4 acc[4][4];
#pragma unroll
  for (int i = 0; i < 4; ++i)
#pragma unroll
    for (int j = 0; j < 4; ++j) acc[i][j] = (f32x4){0.f, 0.f, 0.f, 0.f};

  int mrow = lane & 15;
  int h7 = mrow & 7;
  int qv = lane >> 4;
  int pcA = ((mh << 2) | qv) ^ h7;
  int pcB = ((nh << 2) | qv) ^ h7;

  for (int k0 = 0; k0 < NFEAT; k0 += 32) {
    glds16(gaA1 + k0, lA);
    glds16(gaA2 + k0, lA + 2048);
    glds16(gaB1 + k0, lB);
    glds16(gaB2 + k0, lB + 2048);
    __syncthreads();

    f16x8 af[4], bf[4];
#pragma unroll
    for (int i = 0; i < 4; ++i) {
      af[i] = *reinterpret_cast<const f16x8*>(&As[(i * 16 + mrow) * 64 + pcA * 8]);
      bf[i] = *reinterpret_cast<const f16x8*>(&Bs[(i * 16 + mrow) * 64 + pcB * 8]);
    }
#pragma unroll
    for (int i = 0; i < 4; ++i)
#pragma unroll
      for (int j = 0; j < 4; ++j)
        acc[i][j] = __builtin_amdgcn_mfma_f32_16x16x32_f16(af[i], bf[j], acc[i][j], 0, 0, 0);
    __syncthreads();
  }

  int p = bn >> 8;
  int col = lane & 15, rbase = (lane >> 4) * 4;
#pragma unroll
  for (int i = 0; i < 4; ++i) {
#pragma unroll
    for (int r = 0; r < 4; ++r) {
      int m = bm + wm + i * 16 + rbase + r;
      bool live = (m < N_ATOMS);
      float pw = live ? combW[p * NS + species[m]] : 0.f;
#pragma unroll
      for (int j = 0; j < 4; ++j) {
        int n = bn + wn + j * 16 + col;
        float v = live ? silu(pw * acc[i][j][r]) : 0.f;
        h0f[(size_t)m * 1024 + n] = f2h(v);
      }
    }
  }
}

// ---------------- Kernel C: layer-1 MFMA (B in regs) + W2 dot + seg-sum ----
// 128x64 tile, K=256. B-fragments preloaded to registers from L2-hot W1t
// (2 j-subtiles x 8 k-chunks x 16B). K-loop stages only A via glds16.
__global__ __launch_bounds__(256) void mlp1_mfma(
    const ushort* __restrict__ h0f, const ushort* __restrict__ W1t,
    const float* __restrict__ W2, const int* __restrict__ sid,
    float* __restrict__ out) {
  __shared__ ushort As[64 * 64];   // 8KB
  __shared__ float sout[NSTRUCT];
  int tid = threadIdx.x;
  int bm = blockIdx.y * 128;
  int bn = blockIdx.x * 64;        // global n in [0,1024)
  int p  = bn >> 8;
  int wid = tid >> 6, lane = tid & 63;
  int wm = (wid >> 1) * 64;
  int wn = (wid & 1) * 32;

  if (tid < NSTRUCT) sout[tid] = 0.f;

  int mrow = lane & 15;
  int h7 = mrow & 7;
  int qv = lane >> 4;

  // preload B fragments: n = bn+wn+j*16+mrow, k = ki*32 + qv*8 (+0..7)
  const ushort* wb = W1t + (size_t)p * HID * HID;
  f16x8 breg[2][8];
#pragma unroll
  for (int j = 0; j < 2; ++j) {
    const ushort* row = wb + (size_t)((bn & 255) + wn + j * 16 + mrow) * 256 + qv * 8;
#pragma unroll
    for (int ki = 0; ki < 8; ++ki)
      breg[j][ki] = *reinterpret_cast<const f16x8*>(row + ki * 32);
  }

  int pr = tid >> 3, pc = tid & 7;
  int lg = pc ^ (pr & 7);
  int half = lg >> 2, kc = lg & 3;
  const ushort* gaA1 = h0f + ((size_t)(bm + pr + 64 * half) * 1024 + p * 256 + kc * 8);
  const ushort* gaA2 = gaA1 + (size_t)32 * 1024;
  ushort* lA = As + tid * 8;

  f32x4 acc[4][2];
#pragma unroll
  for (int i = 0; i < 4; ++i)
#pragma unroll
    for (int j = 0; j < 2; ++j) acc[i][j] = (f32x4){0.f, 0.f, 0.f, 0.f};

  int pcA = (((wm >> 6) << 2) | qv) ^ h7;

#pragma unroll
  for (int ki = 0; ki < 8; ++ki) {
    glds16(gaA1 + ki * 32, lA);
    glds16(gaA2 + ki * 32, lA + 2048);
    __syncthreads();

    f16x8 af[4];
#pragma unroll
    for (int i = 0; i < 4; ++i)
      af[i] = *reinterpret_cast<const f16x8*>(&As[(i * 16 + mrow) * 64 + pcA * 8]);
#pragma unroll
    for (int i = 0; i < 4; ++i)
#pragma unroll
      for (int j = 0; j < 2; ++j)
        acc[i][j] = __builtin_amdgcn_mfma_f32_16x16x32_f16(af[i], breg[j][ki], acc[i][j], 0, 0, 0);
    __syncthreads();
  }

  // fused layer-2 + segment-sum epilogue (LDS-staged)
  int col = lane & 15, quad = lane >> 4;
  float w2j0 = W2[bn + wn + col];
  float w2j1 = W2[bn + wn + 16 + col];
#pragma unroll
  for (int i = 0; i < 4; ++i) {
#pragma unroll
    for (int r = 0; r < 4; ++r) {
      float v = silu(acc[i][0][r]) * w2j0 + silu(acc[i][1][r]) * w2j1;
      v += __shfl_xor(v, 1, 64);
      v += __shfl_xor(v, 2, 64);
      v += __shfl_xor(v, 4, 64);
      v += __shfl_xor(v, 8, 64);
      if (col == 0) {
        int m = bm + wm + i * 16 + quad * 4 + r;
        if (m < N_ATOMS) atomicAdd(&sout[sid[m]], v);   // LDS atomic
      }
    }
  }
  __syncthreads();
  if (tid < NSTRUCT) {
    float v = sout[tid];
    if (v != 0.f) atomicAdd(&out[tid], v);              // ~2-3 per block
  }
}

extern "C" void kernel_launch(void* const* d_in, const int* in_sizes, int n_in,
                              void* d_out, int out_size, void* d_ws, size_t ws_size,
                              hipStream_t stream) {
  const float* c0      = (const float*)d_in[0];
  const float* c1      = (const float*)d_in[1];
  const float* c2      = (const float*)d_in[2];
  const float* c3      = (const float*)d_in[3];
  const int*   species = (const int*)d_in[4];
  const int*   sid     = (const int*)d_in[5];
  const float* combW   = (const float*)d_in[6];
  const float* W0      = (const float*)d_in[7];
  const float* W1      = (const float*)d_in[8];
  const float* W2      = (const float*)d_in[9];
  float*       out     = (float*)d_out;

  // ws: fh 83.9MB | W0t 8.4MB | W1t 0.5MB | h0f 21MB = ~114MB
  ushort* fh  = (ushort*)d_ws;
  ushort* W0t = fh  + (size_t)APAD * NFEAT;
  ushort* W1t = W0t + (size_t)NP * HID * NFEAT;
  ushort* h0f = W1t + (size_t)NP * HID * HID;

  prep_kernel<<<PB_TOTAL, 256, 0, stream>>>(c0, c1, c2, c3, W0, W1,
                                            fh, W0t, W1t, out);

  dim3 g2(8, APAD / 128);    // 8 n-tiles x 80 remapped slots (R8 shape)
  gemm0_mfma<<<g2, 256, 0, stream>>>(fh, W0t, combW, species, h0f);

  dim3 g3(16, APAD / 128);   // 16 n-tiles x 80 m-tiles
  mlp1_mfma<<<g3, 256, 0, stream>>>(h0f, W1t, W2, sid, out);
}